// Round 14
// baseline (980.912 us; speedup 1.0000x reference)
//
#include <hip/hip_runtime.h>
#include <cmath>
#include <cstdint>

#define D_MODEL 512
#define NH 8
#define DH 64

static inline int ceil_div(int a, int b) { return (a + b - 1) / b; }

typedef __attribute__((ext_vector_type(8))) short short8;
typedef __attribute__((ext_vector_type(4))) float floatx4;

// fp32 -> bf16 (RNE)
__device__ __forceinline__ unsigned short f2bf(float f) {
  uint32_t u = __float_as_uint(f);
  uint32_t r = (u + 0x7fffu + ((u >> 16) & 1u)) >> 16;
  return (unsigned short)r;
}
__device__ __forceinline__ float bf2f(unsigned short s) {
  return __uint_as_float(((uint32_t)s) << 16);
}

// ---------------- threefry2x32 (JAX-exact) ----------------
#define TF_ROTL(x, r) (((x) << (r)) | ((x) >> (32 - (r))))

__host__ __device__ inline void threefry2x32(uint32_t k0, uint32_t k1,
                                             uint32_t x0, uint32_t x1,
                                             uint32_t* o0, uint32_t* o1) {
  uint32_t ks2 = k0 ^ k1 ^ 0x1BD11BDAu;
  x0 += k0; x1 += k1;
#define TF_R4(a, b, c, d)                                    \
  x0 += x1; x1 = TF_ROTL(x1, a); x1 ^= x0;                   \
  x0 += x1; x1 = TF_ROTL(x1, b); x1 ^= x0;                   \
  x0 += x1; x1 = TF_ROTL(x1, c); x1 ^= x0;                   \
  x0 += x1; x1 = TF_ROTL(x1, d); x1 ^= x0;
  TF_R4(13, 15, 26, 6);  x0 += k1;  x1 += ks2 + 1u;
  TF_R4(17, 29, 16, 24); x0 += ks2; x1 += k0 + 2u;
  TF_R4(13, 15, 26, 6);  x0 += k0;  x1 += k1 + 3u;
  TF_R4(17, 29, 16, 24); x0 += k1;  x1 += ks2 + 4u;
  TF_R4(13, 15, 26, 6);  x0 += ks2; x1 += k0 + 5u;
#undef TF_R4
  *o0 = x0; *o1 = x1;
}

__global__ void idx_kernel(int* __restrict__ idx, int L, int U,
                           uint32_t k0, uint32_t k1) {
  int n = blockIdx.x * 256 + threadIdx.x;
  if (n >= L * U) return;
  uint32_t o0, o1;
  threefry2x32(k0, k1, 0u, (uint32_t)n, &o0, &o1);
  idx[n] = (int)((o0 ^ o1) & (uint32_t)(L - 1));
}

// ---------------- fp32 -> bf16 cast, 4 elems/thread ----------------
__global__ __launch_bounds__(256) void cast_bf16_kernel(
    const float* __restrict__ src, unsigned short* __restrict__ dst, int n) {
  int i = (blockIdx.x * 256 + threadIdx.x) * 4;
  if (i >= n) return;
  float4 v = *(const float4*)(src + i);
  ushort4 o;
  o.x = f2bf(v.x); o.y = f2bf(v.y); o.z = f2bf(v.z); o.w = f2bf(v.w);
  *(ushort4*)(dst + i) = o;
}

// ---------------- embedding + pos encoding, dual fp32/bf16 out ------------
__global__ __launch_bounds__(256) void embed_kernel(
    const float* __restrict__ x_enc, const float* __restrict__ emb_w,
    float* __restrict__ x, unsigned short* __restrict__ xb, int B, int L) {
  int i = blockIdx.x * 256 + threadIdx.x;
  int total = B * L * D_MODEL;
  if (i >= total) return;
  int d = i % D_MODEL;
  int l = (i / D_MODEL) % L;
  int b = i / (D_MODEL * L);
  int lm = (l == 0) ? (L - 1) : (l - 1);
  int lp = (l == L - 1) ? 0 : (l + 1);
  const float* w = emb_w + d * 6;
  const float* xb_in = x_enc + (size_t)b * L * 2;
  float acc = 0.f;
  acc += xb_in[lm * 2 + 0] * w[0] + xb_in[l * 2 + 0] * w[1] + xb_in[lp * 2 + 0] * w[2];
  acc += xb_in[lm * 2 + 1] * w[3] + xb_in[l * 2 + 1] * w[4] + xb_in[lp * 2 + 1] * w[5];
  int j = d >> 1;
  const float coef = -0.017988946039015985f;  // -ln(10000)/512
  float div = expf((float)(2 * j) * coef);
  float ang = (float)l * div;
  float pe = (d & 1) ? cosf(ang) : sinf(ang);
  float v = acc + pe;
  x[i] = v;
  xb[i] = f2bf(v);
}

// ---------------- layer norm over D=512 (plain + dual-output) -------------
__global__ __launch_bounds__(256) void ln_kernel(
    const float* __restrict__ in, const float* __restrict__ g,
    const float* __restrict__ b, float* __restrict__ out) {
  int row = blockIdx.x;
  int t = threadIdx.x;
  const float* xr = in + (size_t)row * D_MODEL;
  float v0 = xr[t], v1 = xr[t + 256];
  __shared__ float red[256];
  red[t] = v0 + v1;
  __syncthreads();
  for (int s = 128; s > 0; s >>= 1) { if (t < s) red[t] += red[t + s]; __syncthreads(); }
  float mean = red[0] * (1.0f / 512.0f);
  __syncthreads();
  float d0 = v0 - mean, d1 = v1 - mean;
  red[t] = d0 * d0 + d1 * d1;
  __syncthreads();
  for (int s = 128; s > 0; s >>= 1) { if (t < s) red[t] += red[t + s]; __syncthreads(); }
  float var = red[0] * (1.0f / 512.0f);
  float rstd = 1.0f / sqrtf(var + 1e-5f);
  float* outr = out + (size_t)row * D_MODEL;
  outr[t]       = d0 * rstd * g[t]       + b[t];
  outr[t + 256] = d1 * rstd * g[t + 256] + b[t + 256];
}

__global__ __launch_bounds__(256) void ln_dual_kernel(
    const float* __restrict__ in, const float* __restrict__ g,
    const float* __restrict__ b, float* __restrict__ out,
    unsigned short* __restrict__ out16) {
  int row = blockIdx.x;
  int t = threadIdx.x;
  const float* xr = in + (size_t)row * D_MODEL;
  float v0 = xr[t], v1 = xr[t + 256];
  __shared__ float red[256];
  red[t] = v0 + v1;
  __syncthreads();
  for (int s = 128; s > 0; s >>= 1) { if (t < s) red[t] += red[t + s]; __syncthreads(); }
  float mean = red[0] * (1.0f / 512.0f);
  __syncthreads();
  float d0 = v0 - mean, d1 = v1 - mean;
  red[t] = d0 * d0 + d1 * d1;
  __syncthreads();
  for (int s = 128; s > 0; s >>= 1) { if (t < s) red[t] += red[t + s]; __syncthreads(); }
  float var = red[0] * (1.0f / 512.0f);
  float rstd = 1.0f / sqrtf(var + 1e-5f);
  float* outr = out + (size_t)row * D_MODEL;
  unsigned short* o16 = out16 + (size_t)row * D_MODEL;
  float r0 = d0 * rstd * g[t] + b[t];
  float r1 = d1 * rstd * g[t + 256] + b[t + 256];
  outr[t] = r0;       o16[t] = f2bf(r0);
  outr[t + 256] = r1; o16[t + 256] = f2bf(r1);
}

// MODE 0: +bias   1: gelu(+bias)   2: +bias +R   3: elu((+bias)*scl*g + bb)
__device__ __forceinline__ float epilogue_apply(int MODE, float v, float r,
                                                float g, float bb, float scl) {
  if (MODE == 1) {
    v = 0.5f * v * (1.0f + erff(v * 0.7071067811865475f));
  } else if (MODE == 2) {
    v += r;
  } else if (MODE == 3) {
    v = v * scl * g + bb;
    v = (v > 0.f) ? v : expm1f(v);
  }
  return v;
}

// ---------------- bf16 MFMA GEMM 64x64, BK=32 (M < 8192) -----------------
// OUT bitmask: 1 = fp32 C, 2 = bf16 C16
template <int MODE, int OUT>
__global__ __launch_bounds__(256) void bgemm_kernel(
    const unsigned short* __restrict__ A, const unsigned short* __restrict__ Bt,
    const float* __restrict__ bias, const float* __restrict__ R,
    const float* __restrict__ gvec, const float* __restrict__ bvec,
    float* __restrict__ C, unsigned short* __restrict__ C16,
    int M, int N, int K, float scl) {
  __shared__ unsigned short Al[64][40];
  __shared__ unsigned short Bl[64][40];
  const int bm = blockIdx.y * 64, bn = blockIdx.x * 64;
  const int tid = threadIdx.x;
  const int wave = tid >> 6, lane = tid & 63;
  const int wm = (wave >> 1) * 32, wn = (wave & 1) * 32;
  const int quad = lane >> 4, l16 = lane & 15;
  const int sr = tid >> 2;
  const int sc = (tid & 3) * 8;
  const unsigned short* Ag = A + (size_t)(bm + sr) * K + sc;
  const unsigned short* Bg = Bt + (size_t)(bn + sr) * K + sc;
  floatx4 zero = {0.f, 0.f, 0.f, 0.f};
  floatx4 acc00 = zero, acc01 = zero, acc10 = zero, acc11 = zero;
  for (int k0 = 0; k0 < K; k0 += 32) {
    short8 a8 = *(const short8*)(Ag + k0);
    short8 b8 = *(const short8*)(Bg + k0);
    *(short8*)&Al[sr][sc] = a8;
    *(short8*)&Bl[sr][sc] = b8;
    __syncthreads();
    short8 af0 = *(const short8*)&Al[wm + l16][quad * 8];
    short8 af1 = *(const short8*)&Al[wm + 16 + l16][quad * 8];
    short8 bf0 = *(const short8*)&Bl[wn + l16][quad * 8];
    short8 bf1 = *(const short8*)&Bl[wn + 16 + l16][quad * 8];
    acc00 = __builtin_amdgcn_mfma_f32_16x16x32_bf16(af0, bf0, acc00, 0, 0, 0);
    acc01 = __builtin_amdgcn_mfma_f32_16x16x32_bf16(af0, bf1, acc01, 0, 0, 0);
    acc10 = __builtin_amdgcn_mfma_f32_16x16x32_bf16(af1, bf0, acc10, 0, 0, 0);
    acc11 = __builtin_amdgcn_mfma_f32_16x16x32_bf16(af1, bf1, acc11, 0, 0, 0);
    __syncthreads();
  }
  floatx4 accs[2][2] = {{acc00, acc01}, {acc10, acc11}};
#pragma unroll
  for (int i = 0; i < 2; ++i) {
#pragma unroll
    for (int j = 0; j < 2; ++j) {
      int col = bn + wn + j * 16 + l16;
#pragma unroll
      for (int p = 0; p < 4; ++p) {
        int row = bm + wm + i * 16 + quad * 4 + p;
        float v = accs[i][j][p] + bias[col];
        v = epilogue_apply(MODE, v, (MODE == 2) ? R[(size_t)row * N + col] : 0.f,
                           (MODE == 3) ? gvec[col] : 0.f,
                           (MODE == 3) ? bvec[col] : 0.f, scl);
        if (OUT & 1) C[(size_t)row * N + col] = v;
        if (OUT & 2) C16[(size_t)row * N + col] = f2bf(v);
      }
    }
  }
}

// ---------------- bf16 MFMA GEMM 128x64, BK=64 (M >= 8192) ----------------
// 4 waves, each owns 32 rows x 64 cols: 16 MFMA per barrier pair (4x the
// 64-tile), 8 k-iters at K=512 (half the barriers). LDS 27.6 KB -> ~5
// blocks/CU; grid (8, M/128) >= 512 = 2 blocks/CU at M=8192. Stride 72
// shorts (36 dwords): frag reads 2-way bank aliasing = free (G4/m136).
template <int MODE, int OUT>
__global__ __launch_bounds__(256) void bgemm128_kernel(
    const unsigned short* __restrict__ A, const unsigned short* __restrict__ Bt,
    const float* __restrict__ bias, const float* __restrict__ R,
    const float* __restrict__ gvec, const float* __restrict__ bvec,
    float* __restrict__ C, unsigned short* __restrict__ C16,
    int M, int N, int K, float scl) {
  __shared__ unsigned short Al[128][72];
  __shared__ unsigned short Bl[64][72];
  const int bm = blockIdx.y * 128, bn = blockIdx.x * 64;
  const int tid = threadIdx.x;
  const int wave = tid >> 6, lane = tid & 63;
  const int wm = wave * 32;
  const int quad = lane >> 4, l16 = lane & 15;
  const int asr = tid >> 1;             // 0..127
  const int asc = (tid & 1) * 32;       // 0 or 32
  const int bsr = tid & 63;             // 0..63
  const int bsc = (tid >> 6) * 16;      // 0,16,32,48
  const unsigned short* Ag = A + (size_t)(bm + asr) * K + asc;
  const unsigned short* Bg = Bt + (size_t)(bn + bsr) * K + bsc;
  floatx4 zero = {0.f, 0.f, 0.f, 0.f};
  floatx4 acc[2][4];
#pragma unroll
  for (int i = 0; i < 2; ++i)
#pragma unroll
    for (int j = 0; j < 4; ++j) acc[i][j] = zero;
  for (int k0 = 0; k0 < K; k0 += 64) {
    short8 a0 = *(const short8*)(Ag + k0 + 0);
    short8 a1 = *(const short8*)(Ag + k0 + 8);
    short8 a2 = *(const short8*)(Ag + k0 + 16);
    short8 a3 = *(const short8*)(Ag + k0 + 24);
    short8 b0 = *(const short8*)(Bg + k0 + 0);
    short8 b1 = *(const short8*)(Bg + k0 + 8);
    *(short8*)&Al[asr][asc + 0]  = a0;
    *(short8*)&Al[asr][asc + 8]  = a1;
    *(short8*)&Al[asr][asc + 16] = a2;
    *(short8*)&Al[asr][asc + 24] = a3;
    *(short8*)&Bl[bsr][bsc + 0]  = b0;
    *(short8*)&Bl[bsr][bsc + 8]  = b1;
    __syncthreads();
#pragma unroll
    for (int ks = 0; ks < 2; ++ks) {
      const int kc = ks * 32 + quad * 8;
      short8 af0 = *(const short8*)&Al[wm + l16][kc];
      short8 af1 = *(const short8*)&Al[wm + 16 + l16][kc];
      short8 bf[4];
#pragma unroll
      for (int j = 0; j < 4; ++j)
        bf[j] = *(const short8*)&Bl[j * 16 + l16][kc];
#pragma unroll
      for (int j = 0; j < 4; ++j) {
        acc[0][j] = __builtin_amdgcn_mfma_f32_16x16x32_bf16(af0, bf[j], acc[0][j], 0, 0, 0);
        acc[1][j] = __builtin_amdgcn_mfma_f32_16x16x32_bf16(af1, bf[j], acc[1][j], 0, 0, 0);
      }
    }
    __syncthreads();
  }
#pragma unroll
  for (int i = 0; i < 2; ++i) {
#pragma unroll
    for (int j = 0; j < 4; ++j) {
      int col = bn + j * 16 + l16;
#pragma unroll
      for (int p = 0; p < 4; ++p) {
        int row = bm + wm + i * 16 + quad * 4 + p;
        float v = acc[i][j][p] + bias[col];
        v = epilogue_apply(MODE, v, (MODE == 2) ? R[(size_t)row * N + col] : 0.f,
                           (MODE == 3) ? gvec[col] : 0.f,
                           (MODE == 3) ? bvec[col] : 0.f, scl);
        if (OUT & 1) C[(size_t)row * N + col] = v;
        if (OUT & 2) C16[(size_t)row * N + col] = f2bf(v);
      }
    }
  }
}

template <int MODE, int OUT>
static void run_bgemm(const unsigned short* A, const unsigned short* Bt,
                      const float* bias, const float* R, const float* g,
                      const float* bb, float* C, unsigned short* C16,
                      int M, int N, int K, float scl, hipStream_t stream) {
  if (M >= 8192) {
    dim3 gg(N / 64, M / 128);
    bgemm128_kernel<MODE, OUT><<<gg, 256, 0, stream>>>(A, Bt, bias, R, g, bb,
                                                       C, C16, M, N, K, scl);
  } else {
    dim3 gg(N / 64, M / 64);
    bgemm_kernel<MODE, OUT><<<gg, 256, 0, stream>>>(A, Bt, bias, R, g, bb, C,
                                                    C16, M, N, K, scl);
  }
}

// ---------------- sparse QK: one BLOCK per (b,l), bf16 K gathers ----------
__global__ __launch_bounds__(256) void sparse_qk_kernel(
    const float* __restrict__ Q, const unsigned short* __restrict__ K16,
    const int* __restrict__ idx, float* __restrict__ QKs, int B, int L,
    int U) {
  int bl = blockIdx.x;  // b*L + l
  int b = bl / L, l = bl - b * L;
  int tid = threadIdx.x;
  int wave = tid >> 6, lane = tid & 63;
  int h = lane >> 3;
  const float4* qr = (const float4*)(Q + (size_t)bl * D_MODEL + lane * 8);
  float4 q0 = qr[0], q1 = qr[1];
  float qv[8] = {q0.x, q0.y, q0.z, q0.w, q1.x, q1.y, q1.z, q1.w};
  const int* idxl = idx + l * U;
  for (int u = wave; u < U; u += 4) {
    int ki = idxl[u];
    short8 k8 = *(const short8*)(K16 + ((size_t)b * L + ki) * D_MODEL + lane * 8);
    float p = 0.f;
#pragma unroll
    for (int e = 0; e < 8; ++e) p += qv[e] * bf2f((unsigned short)k8[e]);
    p += __shfl_xor(p, 1);
    p += __shfl_xor(p, 2);
    p += __shfl_xor(p, 4);
    if ((lane & 7) == 0)
      QKs[(((size_t)(b * NH + h)) * L + l) * U + u] = p;
  }
}

// M[bh*L+l] = max_u(QKs) - sum_u(QKs)/L ; one wave per query, ONE butterfly
__global__ __launch_bounds__(256) void sparse_reduce_kernel(
    const float* __restrict__ QKs, float* __restrict__ Mout, int total,
    int L, int U) {
  int wid = (blockIdx.x * 256 + threadIdx.x) >> 6;
  int lane = threadIdx.x & 63;
  if (wid >= total) return;
  float v = (lane < U) ? QKs[(size_t)wid * U + lane] : -INFINITY;
  float m = v;
#pragma unroll
  for (int k = 32; k; k >>= 1) m = fmaxf(m, __shfl_xor(m, k));
  float sv = (lane < U) ? v : 0.f;
#pragma unroll
  for (int k = 32; k; k >>= 1) sv += __shfl_xor(sv, k);
  if (lane == 0) Mout[wid] = m - sv / (float)L;
}

// ---------------- top-k: barrier-free per-wave selection + rank merge -----
template <int NE>  // NE = L/256 elems per lane
__global__ __launch_bounds__(256) void topk_kernel(
    const float* __restrict__ Mv, int* __restrict__ Mtop, int u) {
  int bh = blockIdx.x;
  int t = threadIdx.x;
  int wave = t >> 6, lane = t & 63;
  const int base = wave * 64 * NE;
  float vals[NE];
  const float* src = Mv + (size_t)bh * (NE * 256);
#pragma unroll
  for (int i = 0; i < NE; ++i) vals[i] = src[base + i * 64 + lane];
  __shared__ float cv[4][40];
  __shared__ int ci[4][40];
  for (int it = 0; it < u; ++it) {
    float bv = -INFINITY;
    int bi = 0x7fffffff;
#pragma unroll
    for (int i = 0; i < NE; ++i) {
      float v = vals[i];
      int ix = base + i * 64 + lane;
      if (v > bv || (v == bv && ix < bi)) { bv = v; bi = ix; }
    }
#pragma unroll
    for (int k = 32; k; k >>= 1) {
      float ov = __shfl_xor(bv, k);
      int oi = __shfl_xor(bi, k);
      if (ov > bv || (ov == bv && oi < bi)) { bv = ov; bi = oi; }
    }
    if (lane == 0) { cv[wave][it] = bv; ci[wave][it] = bi; }
#pragma unroll
    for (int i = 0; i < NE; ++i)
      if (bi == base + i * 64 + lane) vals[i] = -INFINITY;
  }
  __syncthreads();
  if (t < 4 * u) {
    int w = t / u, p = t - w * u;
    float mv = cv[w][p];
    int mi = ci[w][p];
    int rank = p;
    for (int w2 = 0; w2 < 4; ++w2) {
      if (w2 == w) continue;
      int lo = 0, hi = u;
      while (lo < hi) {
        int mid = (lo + hi) >> 1;
        float v2 = cv[w2][mid];
        int i2 = ci[w2][mid];
        if (v2 > mv || (v2 == mv && i2 < mi)) lo = mid + 1;
        else hi = mid;
      }
      rank += lo;
    }
    if (rank < u) Mtop[bh * u + rank] = mi;
  }
}

static void run_topk(const float* Mv, int* Mtop, int L, int u,
                     hipStream_t stream) {
  if (L == 2048)      topk_kernel<8><<<32, 256, 0, stream>>>(Mv, Mtop, u);
  else if (L == 1024) topk_kernel<4><<<32, 256, 0, stream>>>(Mv, Mtop, u);
  else                topk_kernel<2><<<32, 256, 0, stream>>>(Mv, Mtop, u);
}

// ---------------- mean of V over L: split-L partial + atomic --------------
__global__ void vmean_zero_kernel(float* __restrict__ vmean) {
  vmean[blockIdx.x * 256 + threadIdx.x] = 0.f;
}

__global__ __launch_bounds__(256) void vmean_partial_kernel(
    const float* __restrict__ V, float* __restrict__ vmean, int L) {
  int b = blockIdx.y;
  int chunk = blockIdx.x;           // 64 chunks
  int rows = L >> 6;
  int t = threadIdx.x;
  const float* base = V + ((size_t)b * L + (size_t)chunk * rows) * D_MODEL;
  float s0 = 0.f, s1 = 0.f;
  for (int r = 0; r < rows; ++r) {
    s0 += base[(size_t)r * D_MODEL + t];
    s1 += base[(size_t)r * D_MODEL + t + 256];
  }
  float invL = 1.0f / (float)L;
  atomicAdd(&vmean[b * D_MODEL + t], s0 * invL);
  atomicAdd(&vmean[b * D_MODEL + t + 256], s1 * invL);
}

__global__ void fill_ctx_kernel(const float* __restrict__ vmean,
                                float* __restrict__ O, int B, int L) {
  int i = blockIdx.x * 256 + threadIdx.x;
  int total = B * L * D_MODEL;
  if (i >= total) return;
  int dcol = i % D_MODEL;
  int b = i / (D_MODEL * L);
  O[i] = vmean[b * D_MODEL + dcol];
}

// ============== attention as batched GEMM pipeline ==============
__global__ void pack_qred_kernel(const float* __restrict__ Q,
                                 const int* __restrict__ Mtop,
                                 float* __restrict__ qred, int L, int U) {
  int z = blockIdx.x;  // bh
  int b = z / NH, h = z % NH;
  int t = threadIdx.x;
  int d = t & 63;
  for (int r = t >> 6; r < 64; r += 4) {
    float v = 0.f;
    if (r < U) {
      int l = Mtop[z * U + r];
      v = Q[((size_t)(b * L + l)) * D_MODEL + h * DH + d];
    }
    qred[((size_t)z * 64 + r) * 64 + d] = v;
  }
}

#define BK 16
#define PADR 4

// S[z][64][L] = 0.125 * Qred[z](64x64) @ K_z^T ; K_z rows stride 512
__global__ __launch_bounds__(256) void scores_gemm_kernel(
    const float* __restrict__ qred, const float* __restrict__ Km,
    float* __restrict__ S, int L) {
  __shared__ float As[BK][64 + PADR];
  __shared__ float Bs[BK][64 + PADR];
  const int z = blockIdx.y;
  const int b = z / NH, h = z % NH;
  const float* A = qred + (size_t)z * 64 * 64;
  const float* Bt = Km + (size_t)b * L * D_MODEL + h * DH;  // ldb = 512
  float* Sz = S + (size_t)z * 64 * L;
  const int bn = blockIdx.x * 64;
  const int tid = threadIdx.x;
  const int tx = tid & 15, ty = tid >> 4;
  const int lr = tid >> 2;
  const int lc = (tid & 3) << 2;
  float acc[4][4] = {};
  for (int k0 = 0; k0 < 64; k0 += BK) {
    float4 av = *(const float4*)(A + (size_t)lr * 64 + k0 + lc);
    float4 bv = *(const float4*)(Bt + (size_t)(bn + lr) * D_MODEL + k0 + lc);
    As[lc + 0][lr] = av.x; As[lc + 1][lr] = av.y;
    As[lc + 2][lr] = av.z; As[lc + 3][lr] = av.w;
    Bs[lc + 0][lr] = bv.x; Bs[lc + 1][lr] = bv.y;
    Bs[lc + 2][lr] = bv.z; Bs[lc + 3][lr] = bv.w;
    __syncthreads();
#pragma unroll
    for (int kk = 0; kk < BK; ++kk) {
      float4 a4 = *(const float4*)&As[kk][ty << 2];
      float4 b4 = *(const float4*)&Bs[kk][tx << 2];
      float ar[4] = {a4.x, a4.y, a4.z, a4.w};
      float br[4] = {b4.x, b4.y, b4.z, b4.w};
#pragma unroll
      for (int i = 0; i < 4; ++i)
#pragma unroll
        for (int j = 0; j < 4; ++j) acc[i][j] += ar[i] * br[j];
    }
    __syncthreads();
  }
#pragma unroll
  for (int i = 0; i < 4; ++i) {
    float* Sr = Sz + (size_t)((ty << 2) + i) * L + bn;
#pragma unroll
    for (int j = 0; j < 4; ++j) Sr[(tx << 2) + j] = 0.125f * acc[i][j];
  }
}

// ---------------- softmax: one block per (z,row) ----------------
template <int LC>
__global__ __launch_bounds__(256) void softmax_kernel(float* __restrict__ S,
                                                      int U) {
  constexpr int NE = LC / 256;
  int rid = blockIdx.x;
  int z = rid / U, r = rid % U;
  float* row = S + (size_t)z * 64 * LC + (size_t)r * LC;
  int t = threadIdx.x;
  float vals[NE];
  float m = -INFINITY;
#pragma unroll
  for (int i = 0; i < NE; ++i) {
    vals[i] = row[t + i * 256];
    m = fmaxf(m, vals[i]);
  }
  __shared__ float red[256];
  red[t] = m;
  __syncthreads();
  for (int s = 128; s > 0; s >>= 1) { if (t < s) red[t] = fmaxf(red[t], red[t + s]); __syncthreads(); }
  m = red[0];
  __syncthreads();
  float sum = 0.f;
#pragma unroll
  for (int i = 0; i < NE; ++i) {
    vals[i] = expf(vals[i] - m);
    sum += vals[i];
  }
  red[t] = sum;
  __syncthreads();
  for (int s = 128; s > 0; s >>= 1) { if (t < s) red[t] += red[t + s]; __syncthreads(); }
  float inv = 1.0f / red[0];
#pragma unroll
  for (int i = 0; i < NE; ++i) row[t + i * 256] = vals[i] * inv;
}

static void run_softmax(float* S, int L, int U, hipStream_t stream) {
  int blocks = 32 * U;
  if (L == 2048)      softmax_kernel<2048><<<blocks, 256, 0, stream>>>(S, U);
  else if (L == 1024) softmax_kernel<1024><<<blocks, 256, 0, stream>>>(S, U);
  else                softmax_kernel<512><<<blocks, 256, 0, stream>>>(S, U);
}

// zero the selected ctx rows before split-K PV atomics
__global__ void zero_sel_kernel(const int* __restrict__ Mtop,
                                float* __restrict__ O, int L, int U) {
  int z = blockIdx.x;
  int b = z / NH, h = z % NH;
  int t = threadIdx.x;
  int d = t & 63;
  for (int r = t >> 6; r < U; r += 4) {
    int l = Mtop[z * U + r];
    O[((size_t)(b * L + l)) * D_MODEL + h * DH + d] = 0.f;
  }
}

// O[sel rows] += P(UxL) @ V(Lx64), split-K over 128-chunks of L.
#define PV_LC 128

template <int U>
__global__ __launch_bounds__(256) void pv_kernel(
    const float* __restrict__ P, const float* __restrict__ V,
    const int* __restrict__ Mtop, float* __restrict__ O, int L) {
  __shared__ float Pl[U][PV_LC];
  __shared__ float Vl[PV_LC][DH + 4];
  const int z = blockIdx.y;
  const int b = z / NH, h = z % NH;
  const int c0 = blockIdx.x * PV_LC;
  const int tid = threadIdx.x;
  const float* Pz = P + (size_t)z * 64 * L + c0;
  for (int i4 = tid; i4 < U * (PV_LC / 4); i4 += 256) {
    int r = i4 / (PV_LC / 4);
    int lq = (i4 % (PV_LC / 4)) * 4;
    float4 p4 = *(const float4*)(Pz + (size_t)r * L + lq);
    Pl[r][lq + 0] = p4.x; Pl[r][lq + 1] = p4.y;
    Pl[r][lq + 2] = p4.z; Pl[r][lq + 3] = p4.w;
  }
  const float* Vb = V + ((size_t)b * L + c0) * D_MODEL + h * DH;
  for (int i4 = tid; i4 < PV_LC * (DH / 4); i4 += 256) {
    int l = i4 >> 4;
    int d4 = (i4 & 15) * 4;
    float4 v4 = *(const float4*)(Vb + (size_t)l * D_MODEL + d4);
    Vl[l][d4 + 0] = v4.x; Vl[l][d4 + 1] = v4.y;
    Vl[l][d4 + 2] = v4.z; Vl[l][d4 + 3] = v4.w;
  }
  __syncthreads();
  const int wave = tid >> 6, lane = tid & 63;
  constexpr int NJ = (U + 3) / 4;
  float acc[NJ] = {};
  for (int l = 0; l < PV_LC; ++l) {
    float vv = Vl[l][lane];
#pragma unroll
    for (int j = 0; j < NJ; ++j) {
      int r = wave + 4 * j;
      if (r < U) acc[j] += Pl[r][l] * vv;
    }
  }
#pragma unroll
  for (int j = 0; j < NJ; ++j) {
    int r = wave + 4 * j;
    if (r < U) {
      int ml = Mtop[z * U + r];
      atomicAdd(&O[((size_t)(b * L + ml)) * D_MODEL + h * DH + lane], acc[j]);
    }
  }
}

static void run_pv(const float* P, const float* V, const int* Mtop, float* O,
                   int L, int U, hipStream_t stream) {
  dim3 gg(L / PV_LC, 32);
  if (U == 40)      pv_kernel<40><<<gg, 256, 0, stream>>>(P, V, Mtop, O, L);
  else if (U == 35) pv_kernel<35><<<gg, 256, 0, stream>>>(P, V, Mtop, O, L);
  else              pv_kernel<64><<<gg, 256, 0, stream>>>(P, V, Mtop, O, L);
}

// ---------------- im2col (circular, K=3) -> bf16 --------------------------
__global__ void im2col_kernel(const float* __restrict__ X,
                              unsigned short* __restrict__ Y, int B, int L) {
  int i = blockIdx.x * 256 + threadIdx.x;
  int total = B * L * 1536;
  if (i >= total) return;
  int ck = i % 1536;
  int l = (i / 1536) % L;
  int b = i / (1536 * L);
  int c = ck / 3, k = ck % 3;
  int lm = l + k - 1;
  if (lm < 0) lm += L;
  else if (lm >= L) lm -= L;
  Y[i] = f2bf(X[((size_t)(b * L + lm)) * D_MODEL + c]);
}

// ---------------- maxpool k=3 s=2, dual fp32/bf16 out ---------------------
__global__ void maxpool_kernel(const float* __restrict__ Y,
                               float* __restrict__ X,
                               unsigned short* __restrict__ Xb, int B, int L) {
  int Lo = L / 2;
  int i = blockIdx.x * 256 + threadIdx.x;
  int total = B * Lo * D_MODEL;
  if (i >= total) return;
  int d = i % D_MODEL;
  int lp = (i / D_MODEL) % Lo;
  int b = i / (D_MODEL * Lo);
  int l0 = 2 * lp - 1;
  float m = -INFINITY;
#pragma unroll
  for (int k = 0; k < 3; ++k) {
    int l = l0 + k;
    if (l >= 0 && l < L) m = fmaxf(m, Y[((size_t)(b * L + l)) * D_MODEL + d]);
  }
  X[i] = m;
  Xb[i] = f2bf(m);
}

// ==========================================================================
extern "C" void kernel_launch(void* const* d_in, const int* in_sizes, int n_in,
                              void* d_out, int out_size, void* d_ws,
                              size_t ws_size, hipStream_t stream) {
  const float* x_enc  = (const float*)d_in[0];
  const float* emb_w  = (const float*)d_in[1];
  const float* Wq     = (const float*)d_in[2];
  const float* bq     = (const float*)d_in[3];
  const float* Wk     = (const float*)d_in[4];
  const float* bk     = (const float*)d_in[5];
  const float* Wv     = (const float*)d_in[6];
  const float* bv     = (const float*)d_in[7];
  const float* Wo     = (const float*)d_in[8];
  const float* bo     = (const float*)d_in[9];
  const float* ln1_g  = (const float*)d_in[10];
  const float* ln1_b  = (const float*)d_in[11];
  const float* ff_w1  = (const float*)d_in[12];
  const float* ff_b1  = (const float*)d_in[13];
  const float* ff_w2  = (const float*)d_in[14];
  const float* ff_b2  = (const float*)d_in[15];
  const float* ln2_g  = (const float*)d_in[16];
  const float* ln2_b  = (const float*)d_in[17];
  const float* cv_w   = (const float*)d_in[18];
  const float* cv_b   = (const float*)d_in[19];
  const float* bn_g   = (const float*)d_in[20];
  const float* bn_b   = (const float*)d_in[21];
  const float* norm_g = (const float*)d_in[22];
  const float* norm_b = (const float*)d_in[23];

  const int B = 4, L0 = 2048, EL = 3;
  const size_t SZ = (size_t)B * 2048 * 512;
  float* ws   = (float*)d_ws;
  float* xbuf = ws;
  float* ebuf = ws + SZ;   // layer0 xb16; pre-LN temp; QKs; Sbuf
  float* qbuf = ws + 2 * SZ;
  float* kbuf = ws + 3 * SZ;
  float* vbuf = ws + 4 * SZ;
  float* obuf = ws + 5 * SZ;
  float* sm   = ws + 6 * SZ;
  int*   d_idx   = (int*)sm;
  float* d_M     = sm + 81920;
  int*   d_Mtop  = (int*)(sm + 81920 + 65536);
  float* d_vmean = sm + 81920 + 65536 + 1280;
  float* qred    = sm;    // reuses idx+M region (dead post-topk)
  float* QKs     = ebuf;
  float* Sbuf    = ebuf;

  const float inv_s = 1.0f / sqrtf(1.0f + 1e-5f);
  auto cast = [&](const float* s, unsigned short* d, int n) {
    cast_bf16_kernel<<<ceil_div(n / 4, 256), 256, 0, stream>>>(s, d, n);
  };

  // layer-0 x bf16 fused into embed (-> ebuf)
  embed_kernel<<<ceil_div(B * L0 * D_MODEL, 256), 256, 0, stream>>>(
      x_enc, emb_w, xbuf, (unsigned short*)ebuf, B, L0);
  unsigned short* xb16 = (unsigned short*)ebuf;  // current layer's bf16 x

  int L = L0;
  for (int i = 0; i < EL; ++i) {
    const int M_ = B * L;
    int c = 5 * (int)ceil(log((double)L));
    int U = c < L ? c : L;
    const float* Wq_i = Wq + (size_t)i * 512 * 512;
    const float* Wk_i = Wk + (size_t)i * 512 * 512;
    const float* Wv_i = Wv + (size_t)i * 512 * 512;
    const float* Wo_i = Wo + (size_t)i * 512 * 512;
    const float* w1_i = ff_w1 + (size_t)i * 512 * 512;
    const float* w2_i = ff_w2 + (size_t)i * 512 * 512;

    // QKV bf16 MFMA. K dual-writes fp32 kbuf (scores) + bf16 k16 (gathers).
    unsigned short* wq16 = (unsigned short*)obuf;
    unsigned short* wk16 = wq16 + 262144;
    unsigned short* wv16 = wq16 + 524288;
    unsigned short* k16  = wq16 + 1048576;  // obuf bytes [2MB, 2MB+M_*1KB)
    {
      cast(Wq_i, wq16, 512 * 512);
      cast(Wk_i, wk16, 512 * 512);
      cast(Wv_i, wv16, 512 * 512);
      run_bgemm<0, 1>(xb16, wq16, bq + i * 512, nullptr, nullptr, nullptr,
                      qbuf, nullptr, M_, 512, 512, 0.f, stream);
      run_bgemm<0, 3>(xb16, wk16, bk + i * 512, nullptr, nullptr, nullptr,
                      kbuf, k16, M_, 512, 512, 0.f, stream);
      run_bgemm<0, 1>(xb16, wv16, bv + i * 512, nullptr, nullptr, nullptr,
                      vbuf, nullptr, M_, 512, 512, 0.f, stream);
    }

    uint32_t lk0, lk1, k20, k21;
    threefry2x32(0u, 42u, 0u, (uint32_t)i, &lk0, &lk1);
    threefry2x32(lk0, lk1, 0u, 1u, &k20, &k21);
    idx_kernel<<<ceil_div(L * U, 256), 256, 0, stream>>>(d_idx, L, U, k20, k21);

    sparse_qk_kernel<<<B * L, 256, 0, stream>>>(qbuf, k16, d_idx, QKs, B, L, U);
    sparse_reduce_kernel<<<ceil_div(B * NH * L * 64, 256), 256, 0, stream>>>(
        QKs, d_M, B * NH * L, L, U);
    run_topk(d_M, d_Mtop, L, U, stream);
    vmean_zero_kernel<<<8, 256, 0, stream>>>(d_vmean);
    vmean_partial_kernel<<<dim3(64, B), 256, 0, stream>>>(vbuf, d_vmean, L);
    fill_ctx_kernel<<<ceil_div(B * L * D_MODEL, 256), 256, 0, stream>>>(
        d_vmean, obuf, B, L);

    pack_qred_kernel<<<B * NH, 256, 0, stream>>>(qbuf, d_Mtop, qred, L, U);
    scores_gemm_kernel<<<dim3(L / 64, B * NH), 256, 0, stream>>>(qred, kbuf,
                                                                 Sbuf, L);
    run_softmax(Sbuf, L, U, stream);
    zero_sel_kernel<<<B * NH, 256, 0, stream>>>(d_Mtop, obuf, L, U);
    run_pv(Sbuf, vbuf, d_Mtop, obuf, L, U, stream);

    // O-proj: ctx cast -> qbuf shorts (Q dead), Wo -> kbuf shorts (K dead)
    unsigned short* ab16 = (unsigned short*)qbuf;
    unsigned short* wb16 = (unsigned short*)kbuf;
    cast(obuf, ab16, M_ * 512);
    cast(Wo_i, wb16, 512 * 512);
    run_bgemm<2, 1>(ab16, wb16, bo + i * 512, xbuf, nullptr, nullptr, ebuf,
                    nullptr, M_, 512, 512, 0.f, stream);
    // ln1 dual-writes x fp32 + bf16 (FF1 A input) -> qbuf shorts
    ln_dual_kernel<<<M_, 256, 0, stream>>>(ebuf, ln1_g + i * 512,
                                           ln1_b + i * 512, xbuf, ab16);

    // FF1: bf16-only output (consumed solely as FF2's A) -> obuf shorts
    unsigned short* ff1b16 = (unsigned short*)obuf;
    cast(w1_i, wb16, 512 * 512);
    run_bgemm<1, 2>(ab16, wb16, ff_b1 + i * 512, nullptr, nullptr, nullptr,
                    nullptr, ff1b16, M_, 512, 512, 0.f, stream);
    // FF2 (+residual) -> ebuf fp32
    cast(w2_i, wb16, 512 * 512);
    run_bgemm<2, 1>(ff1b16, wb16, ff_b2 + i * 512, xbuf, nullptr, nullptr,
                    ebuf, nullptr, M_, 512, 512, 0.f, stream);
    ln_kernel<<<M_, 256, 0, stream>>>(ebuf, ln2_g + i * 512, ln2_b + i * 512, xbuf);

    if (i < EL - 1) {
      // conv distill: im2col -> qbuf(+kbuf) shorts, weights -> vbuf shorts
      unsigned short* imb16 = (unsigned short*)qbuf;
      unsigned short* wb16c = (unsigned short*)vbuf;
      im2col_kernel<<<ceil_div(B * L * 1536, 256), 256, 0, stream>>>(xbuf, imb16, B, L);
      cast(cv_w + (size_t)i * 512 * 1536, wb16c, 512 * 1536);
      run_bgemm<3, 1>(imb16, wb16c, cv_b + i * 512, nullptr, bn_g + i * 512,
                      bn_b + i * 512, ebuf, nullptr, M_, 512, 1536, inv_s,
                      stream);
      // maxpool dual-writes next-layer x fp32 + bf16 @ vbuf tail (V dead;
      // next layer's V-proj writes only vbuf[0, M_/2*512*4B) -- no overlap)
      xb16 = (unsigned short*)vbuf + 6291456;  // byte offset 12.6MB
      maxpool_kernel<<<ceil_div(B * (L / 2) * D_MODEL, 256), 256, 0, stream>>>(
          ebuf, xbuf, xb16, B, L);
      L /= 2;
    }
  }

  ln_kernel<<<B * L, 256, 0, stream>>>(xbuf, norm_g, norm_b, (float*)d_out);
}

// Round 15
// 971.282 us; speedup vs baseline: 1.0099x; 1.0099x over previous
//
#include <hip/hip_runtime.h>
#include <cmath>
#include <cstdint>

#define D_MODEL 512
#define NH 8
#define DH 64

static inline int ceil_div(int a, int b) { return (a + b - 1) / b; }

typedef __attribute__((ext_vector_type(8))) short short8;
typedef __attribute__((ext_vector_type(4))) float floatx4;

// fp32 -> bf16 (RNE)
__device__ __forceinline__ unsigned short f2bf(float f) {
  uint32_t u = __float_as_uint(f);
  uint32_t r = (u + 0x7fffu + ((u >> 16) & 1u)) >> 16;
  return (unsigned short)r;
}
__device__ __forceinline__ float bf2f(unsigned short s) {
  return __uint_as_float(((uint32_t)s) << 16);
}

// ---------------- threefry2x32 (JAX-exact) ----------------
#define TF_ROTL(x, r) (((x) << (r)) | ((x) >> (32 - (r))))

__host__ __device__ inline void threefry2x32(uint32_t k0, uint32_t k1,
                                             uint32_t x0, uint32_t x1,
                                             uint32_t* o0, uint32_t* o1) {
  uint32_t ks2 = k0 ^ k1 ^ 0x1BD11BDAu;
  x0 += k0; x1 += k1;
#define TF_R4(a, b, c, d)                                    \
  x0 += x1; x1 = TF_ROTL(x1, a); x1 ^= x0;                   \
  x0 += x1; x1 = TF_ROTL(x1, b); x1 ^= x0;                   \
  x0 += x1; x1 = TF_ROTL(x1, c); x1 ^= x0;                   \
  x0 += x1; x1 = TF_ROTL(x1, d); x1 ^= x0;
  TF_R4(13, 15, 26, 6);  x0 += k1;  x1 += ks2 + 1u;
  TF_R4(17, 29, 16, 24); x0 += ks2; x1 += k0 + 2u;
  TF_R4(13, 15, 26, 6);  x0 += k0;  x1 += k1 + 3u;
  TF_R4(17, 29, 16, 24); x0 += k1;  x1 += ks2 + 4u;
  TF_R4(13, 15, 26, 6);  x0 += ks2; x1 += k0 + 5u;
#undef TF_R4
  *o0 = x0; *o1 = x1;
}

__global__ void idx_kernel(int* __restrict__ idx, int L, int U,
                           uint32_t k0, uint32_t k1) {
  int n = blockIdx.x * 256 + threadIdx.x;
  if (n >= L * U) return;
  uint32_t o0, o1;
  threefry2x32(k0, k1, 0u, (uint32_t)n, &o0, &o1);
  idx[n] = (int)((o0 ^ o1) & (uint32_t)(L - 1));
}

// ---------------- fp32 -> bf16 cast, 4 elems/thread ----------------
__global__ __launch_bounds__(256) void cast_bf16_kernel(
    const float* __restrict__ src, unsigned short* __restrict__ dst, int n) {
  int i = (blockIdx.x * 256 + threadIdx.x) * 4;
  if (i >= n) return;
  float4 v = *(const float4*)(src + i);
  ushort4 o;
  o.x = f2bf(v.x); o.y = f2bf(v.y); o.z = f2bf(v.z); o.w = f2bf(v.w);
  *(ushort4*)(dst + i) = o;
}

// ---------------- embedding + pos encoding, dual fp32/bf16 out ------------
__global__ __launch_bounds__(256) void embed_kernel(
    const float* __restrict__ x_enc, const float* __restrict__ emb_w,
    float* __restrict__ x, unsigned short* __restrict__ xb, int B, int L) {
  int i = blockIdx.x * 256 + threadIdx.x;
  int total = B * L * D_MODEL;
  if (i >= total) return;
  int d = i % D_MODEL;
  int l = (i / D_MODEL) % L;
  int b = i / (D_MODEL * L);
  int lm = (l == 0) ? (L - 1) : (l - 1);
  int lp = (l == L - 1) ? 0 : (l + 1);
  const float* w = emb_w + d * 6;
  const float* xb_in = x_enc + (size_t)b * L * 2;
  float acc = 0.f;
  acc += xb_in[lm * 2 + 0] * w[0] + xb_in[l * 2 + 0] * w[1] + xb_in[lp * 2 + 0] * w[2];
  acc += xb_in[lm * 2 + 1] * w[3] + xb_in[l * 2 + 1] * w[4] + xb_in[lp * 2 + 1] * w[5];
  int j = d >> 1;
  const float coef = -0.017988946039015985f;  // -ln(10000)/512
  float div = expf((float)(2 * j) * coef);
  float ang = (float)l * div;
  float pe = (d & 1) ? cosf(ang) : sinf(ang);
  float v = acc + pe;
  x[i] = v;
  xb[i] = f2bf(v);
}

// ---------------- layer norm over D=512 (plain + dual-output) -------------
__global__ __launch_bounds__(256) void ln_kernel(
    const float* __restrict__ in, const float* __restrict__ g,
    const float* __restrict__ b, float* __restrict__ out) {
  int row = blockIdx.x;
  int t = threadIdx.x;
  const float* xr = in + (size_t)row * D_MODEL;
  float v0 = xr[t], v1 = xr[t + 256];
  __shared__ float red[256];
  red[t] = v0 + v1;
  __syncthreads();
  for (int s = 128; s > 0; s >>= 1) { if (t < s) red[t] += red[t + s]; __syncthreads(); }
  float mean = red[0] * (1.0f / 512.0f);
  __syncthreads();
  float d0 = v0 - mean, d1 = v1 - mean;
  red[t] = d0 * d0 + d1 * d1;
  __syncthreads();
  for (int s = 128; s > 0; s >>= 1) { if (t < s) red[t] += red[t + s]; __syncthreads(); }
  float var = red[0] * (1.0f / 512.0f);
  float rstd = 1.0f / sqrtf(var + 1e-5f);
  float* outr = out + (size_t)row * D_MODEL;
  outr[t]       = d0 * rstd * g[t]       + b[t];
  outr[t + 256] = d1 * rstd * g[t + 256] + b[t + 256];
}

__global__ __launch_bounds__(256) void ln_dual_kernel(
    const float* __restrict__ in, const float* __restrict__ g,
    const float* __restrict__ b, float* __restrict__ out,
    unsigned short* __restrict__ out16) {
  int row = blockIdx.x;
  int t = threadIdx.x;
  const float* xr = in + (size_t)row * D_MODEL;
  float v0 = xr[t], v1 = xr[t + 256];
  __shared__ float red[256];
  red[t] = v0 + v1;
  __syncthreads();
  for (int s = 128; s > 0; s >>= 1) { if (t < s) red[t] += red[t + s]; __syncthreads(); }
  float mean = red[0] * (1.0f / 512.0f);
  __syncthreads();
  float d0 = v0 - mean, d1 = v1 - mean;
  red[t] = d0 * d0 + d1 * d1;
  __syncthreads();
  for (int s = 128; s > 0; s >>= 1) { if (t < s) red[t] += red[t + s]; __syncthreads(); }
  float var = red[0] * (1.0f / 512.0f);
  float rstd = 1.0f / sqrtf(var + 1e-5f);
  float* outr = out + (size_t)row * D_MODEL;
  unsigned short* o16 = out16 + (size_t)row * D_MODEL;
  float r0 = d0 * rstd * g[t] + b[t];
  float r1 = d1 * rstd * g[t + 256] + b[t + 256];
  outr[t] = r0;       o16[t] = f2bf(r0);
  outr[t + 256] = r1; o16[t + 256] = f2bf(r1);
}

// MODE 0: +bias   1: gelu(+bias)   2: +bias +R   3: elu((+bias)*scl*g + bb)
__device__ __forceinline__ float epilogue_apply(int MODE, float v, float r,
                                                float g, float bb, float scl) {
  if (MODE == 1) {
    v = 0.5f * v * (1.0f + erff(v * 0.7071067811865475f));
  } else if (MODE == 2) {
    v += r;
  } else if (MODE == 3) {
    v = v * scl * g + bb;
    v = (v > 0.f) ? v : expm1f(v);
  }
  return v;
}

// ---------------- bf16 MFMA GEMM 64x64, BK=32 ------------------------------
// XCD swizzle: blockIdx.x = M-block (gridX multiple of 8), so with
// round-robin bid->XCD all N-blocks of one A row-tile share an XCD; the
// per-XCD A slice (M/8 x K bf16 <= 3 MB) fits its 4 MB L2 -> A fetched
// ~once instead of ~4x (R14: FETCH 99 MB vs ~43 ideal).
// OUT bitmask: 1 = fp32 C, 2 = bf16 C16
template <int MODE, int OUT>
__global__ __launch_bounds__(256) void bgemm_kernel(
    const unsigned short* __restrict__ A, const unsigned short* __restrict__ Bt,
    const float* __restrict__ bias, const float* __restrict__ R,
    const float* __restrict__ gvec, const float* __restrict__ bvec,
    float* __restrict__ C, unsigned short* __restrict__ C16,
    int M, int N, int K, float scl) {
  __shared__ unsigned short Al[64][40];
  __shared__ unsigned short Bl[64][40];
  const int bm = blockIdx.x * 64, bn = blockIdx.y * 64;  // x = M (swizzle)
  const int tid = threadIdx.x;
  const int wave = tid >> 6, lane = tid & 63;
  const int wm = (wave >> 1) * 32, wn = (wave & 1) * 32;
  const int quad = lane >> 4, l16 = lane & 15;
  const int sr = tid >> 2;
  const int sc = (tid & 3) * 8;
  const unsigned short* Ag = A + (size_t)(bm + sr) * K + sc;
  const unsigned short* Bg = Bt + (size_t)(bn + sr) * K + sc;
  floatx4 zero = {0.f, 0.f, 0.f, 0.f};
  floatx4 acc00 = zero, acc01 = zero, acc10 = zero, acc11 = zero;
  for (int k0 = 0; k0 < K; k0 += 32) {
    short8 a8 = *(const short8*)(Ag + k0);
    short8 b8 = *(const short8*)(Bg + k0);
    *(short8*)&Al[sr][sc] = a8;
    *(short8*)&Bl[sr][sc] = b8;
    __syncthreads();
    short8 af0 = *(const short8*)&Al[wm + l16][quad * 8];
    short8 af1 = *(const short8*)&Al[wm + 16 + l16][quad * 8];
    short8 bf0 = *(const short8*)&Bl[wn + l16][quad * 8];
    short8 bf1 = *(const short8*)&Bl[wn + 16 + l16][quad * 8];
    acc00 = __builtin_amdgcn_mfma_f32_16x16x32_bf16(af0, bf0, acc00, 0, 0, 0);
    acc01 = __builtin_amdgcn_mfma_f32_16x16x32_bf16(af0, bf1, acc01, 0, 0, 0);
    acc10 = __builtin_amdgcn_mfma_f32_16x16x32_bf16(af1, bf0, acc10, 0, 0, 0);
    acc11 = __builtin_amdgcn_mfma_f32_16x16x32_bf16(af1, bf1, acc11, 0, 0, 0);
    __syncthreads();
  }
  floatx4 accs[2][2] = {{acc00, acc01}, {acc10, acc11}};
#pragma unroll
  for (int i = 0; i < 2; ++i) {
#pragma unroll
    for (int j = 0; j < 2; ++j) {
      int col = bn + wn + j * 16 + l16;
#pragma unroll
      for (int p = 0; p < 4; ++p) {
        int row = bm + wm + i * 16 + quad * 4 + p;
        float v = accs[i][j][p] + bias[col];
        v = epilogue_apply(MODE, v, (MODE == 2) ? R[(size_t)row * N + col] : 0.f,
                           (MODE == 3) ? gvec[col] : 0.f,
                           (MODE == 3) ? bvec[col] : 0.f, scl);
        if (OUT & 1) C[(size_t)row * N + col] = v;
        if (OUT & 2) C16[(size_t)row * N + col] = f2bf(v);
      }
    }
  }
}

// ---------------- bf16 MFMA GEMM 128x64, BK=64 (conv K=1536 only) ---------
template <int MODE, int OUT>
__global__ __launch_bounds__(256) void bgemm128_kernel(
    const unsigned short* __restrict__ A, const unsigned short* __restrict__ Bt,
    const float* __restrict__ bias, const float* __restrict__ R,
    const float* __restrict__ gvec, const float* __restrict__ bvec,
    float* __restrict__ C, unsigned short* __restrict__ C16,
    int M, int N, int K, float scl) {
  __shared__ unsigned short Al[128][72];
  __shared__ unsigned short Bl[64][72];
  const int bm = blockIdx.x * 128, bn = blockIdx.y * 64;  // x = M (swizzle)
  const int tid = threadIdx.x;
  const int wave = tid >> 6, lane = tid & 63;
  const int wm = wave * 32;
  const int quad = lane >> 4, l16 = lane & 15;
  const int asr = tid >> 1;
  const int asc = (tid & 1) * 32;
  const int bsr = tid & 63;
  const int bsc = (tid >> 6) * 16;
  const unsigned short* Ag = A + (size_t)(bm + asr) * K + asc;
  const unsigned short* Bg = Bt + (size_t)(bn + bsr) * K + bsc;
  floatx4 zero = {0.f, 0.f, 0.f, 0.f};
  floatx4 acc[2][4];
#pragma unroll
  for (int i = 0; i < 2; ++i)
#pragma unroll
    for (int j = 0; j < 4; ++j) acc[i][j] = zero;
  for (int k0 = 0; k0 < K; k0 += 64) {
    short8 a0 = *(const short8*)(Ag + k0 + 0);
    short8 a1 = *(const short8*)(Ag + k0 + 8);
    short8 a2 = *(const short8*)(Ag + k0 + 16);
    short8 a3 = *(const short8*)(Ag + k0 + 24);
    short8 b0 = *(const short8*)(Bg + k0 + 0);
    short8 b1 = *(const short8*)(Bg + k0 + 8);
    *(short8*)&Al[asr][asc + 0]  = a0;
    *(short8*)&Al[asr][asc + 8]  = a1;
    *(short8*)&Al[asr][asc + 16] = a2;
    *(short8*)&Al[asr][asc + 24] = a3;
    *(short8*)&Bl[bsr][bsc + 0]  = b0;
    *(short8*)&Bl[bsr][bsc + 8]  = b1;
    __syncthreads();
#pragma unroll
    for (int ks = 0; ks < 2; ++ks) {
      const int kc = ks * 32 + quad * 8;
      short8 af0 = *(const short8*)&Al[wm + l16][kc];
      short8 af1 = *(const short8*)&Al[wm + 16 + l16][kc];
      short8 bf[4];
#pragma unroll
      for (int j = 0; j < 4; ++j)
        bf[j] = *(const short8*)&Bl[j * 16 + l16][kc];
#pragma unroll
      for (int j = 0; j < 4; ++j) {
        acc[0][j] = __builtin_amdgcn_mfma_f32_16x16x32_bf16(af0, bf[j], acc[0][j], 0, 0, 0);
        acc[1][j] = __builtin_amdgcn_mfma_f32_16x16x32_bf16(af1, bf[j], acc[1][j], 0, 0, 0);
      }
    }
    __syncthreads();
  }
#pragma unroll
  for (int i = 0; i < 2; ++i) {
#pragma unroll
    for (int j = 0; j < 4; ++j) {
      int col = bn + j * 16 + l16;
#pragma unroll
      for (int p = 0; p < 4; ++p) {
        int row = bm + wm + i * 16 + quad * 4 + p;
        float v = acc[i][j][p] + bias[col];
        v = epilogue_apply(MODE, v, (MODE == 2) ? R[(size_t)row * N + col] : 0.f,
                           (MODE == 3) ? gvec[col] : 0.f,
                           (MODE == 3) ? bvec[col] : 0.f, scl);
        if (OUT & 1) C[(size_t)row * N + col] = v;
        if (OUT & 2) C16[(size_t)row * N + col] = f2bf(v);
      }
    }
  }
}

template <int MODE, int OUT>
static void run_bgemm(const unsigned short* A, const unsigned short* Bt,
                      const float* bias, const float* R, const float* g,
                      const float* bb, float* C, unsigned short* C16,
                      int M, int N, int K, float scl, hipStream_t stream) {
  if (K >= 1536 && M >= 8192) {
    dim3 gg(M / 128, N / 64);  // x = M-blocks (XCD swizzle)
    bgemm128_kernel<MODE, OUT><<<gg, 256, 0, stream>>>(A, Bt, bias, R, g, bb,
                                                       C, C16, M, N, K, scl);
  } else {
    dim3 gg(M / 64, N / 64);   // x = M-blocks (XCD swizzle)
    bgemm_kernel<MODE, OUT><<<gg, 256, 0, stream>>>(A, Bt, bias, R, g, bb, C,
                                                    C16, M, N, K, scl);
  }
}

// ---------------- sparse QK: one BLOCK per (b,l), bf16 K gathers ----------
__global__ __launch_bounds__(256) void sparse_qk_kernel(
    const float* __restrict__ Q, const unsigned short* __restrict__ K16,
    const int* __restrict__ idx, float* __restrict__ QKs, int B, int L,
    int U) {
  int bl = blockIdx.x;  // b*L + l
  int b = bl / L, l = bl - b * L;
  int tid = threadIdx.x;
  int wave = tid >> 6, lane = tid & 63;
  int h = lane >> 3;
  const float4* qr = (const float4*)(Q + (size_t)bl * D_MODEL + lane * 8);
  float4 q0 = qr[0], q1 = qr[1];
  float qv[8] = {q0.x, q0.y, q0.z, q0.w, q1.x, q1.y, q1.z, q1.w};
  const int* idxl = idx + l * U;
  for (int u = wave; u < U; u += 4) {
    int ki = idxl[u];
    short8 k8 = *(const short8*)(K16 + ((size_t)b * L + ki) * D_MODEL + lane * 8);
    float p = 0.f;
#pragma unroll
    for (int e = 0; e < 8; ++e) p += qv[e] * bf2f((unsigned short)k8[e]);
    p += __shfl_xor(p, 1);
    p += __shfl_xor(p, 2);
    p += __shfl_xor(p, 4);
    if ((lane & 7) == 0)
      QKs[(((size_t)(b * NH + h)) * L + l) * U + u] = p;
  }
}

// M[bh*L+l] = max_u(QKs) - sum_u(QKs)/L ; one wave per query, ONE butterfly
__global__ __launch_bounds__(256) void sparse_reduce_kernel(
    const float* __restrict__ QKs, float* __restrict__ Mout, int total,
    int L, int U) {
  int wid = (blockIdx.x * 256 + threadIdx.x) >> 6;
  int lane = threadIdx.x & 63;
  if (wid >= total) return;
  float v = (lane < U) ? QKs[(size_t)wid * U + lane] : -INFINITY;
  float m = v;
#pragma unroll
  for (int k = 32; k; k >>= 1) m = fmaxf(m, __shfl_xor(m, k));
  float sv = (lane < U) ? v : 0.f;
#pragma unroll
  for (int k = 32; k; k >>= 1) sv += __shfl_xor(sv, k);
  if (lane == 0) Mout[wid] = m - sv / (float)L;
}

// ---------------- top-k: barrier-free per-wave selection + rank merge -----
template <int NE>  // NE = L/256 elems per lane
__global__ __launch_bounds__(256) void topk_kernel(
    const float* __restrict__ Mv, int* __restrict__ Mtop, int u) {
  int bh = blockIdx.x;
  int t = threadIdx.x;
  int wave = t >> 6, lane = t & 63;
  const int base = wave * 64 * NE;
  float vals[NE];
  const float* src = Mv + (size_t)bh * (NE * 256);
#pragma unroll
  for (int i = 0; i < NE; ++i) vals[i] = src[base + i * 64 + lane];
  __shared__ float cv[4][40];
  __shared__ int ci[4][40];
  for (int it = 0; it < u; ++it) {
    float bv = -INFINITY;
    int bi = 0x7fffffff;
#pragma unroll
    for (int i = 0; i < NE; ++i) {
      float v = vals[i];
      int ix = base + i * 64 + lane;
      if (v > bv || (v == bv && ix < bi)) { bv = v; bi = ix; }
    }
#pragma unroll
    for (int k = 32; k; k >>= 1) {
      float ov = __shfl_xor(bv, k);
      int oi = __shfl_xor(bi, k);
      if (ov > bv || (ov == bv && oi < bi)) { bv = ov; bi = oi; }
    }
    if (lane == 0) { cv[wave][it] = bv; ci[wave][it] = bi; }
#pragma unroll
    for (int i = 0; i < NE; ++i)
      if (bi == base + i * 64 + lane) vals[i] = -INFINITY;
  }
  __syncthreads();
  if (t < 4 * u) {
    int w = t / u, p = t - w * u;
    float mv = cv[w][p];
    int mi = ci[w][p];
    int rank = p;
    for (int w2 = 0; w2 < 4; ++w2) {
      if (w2 == w) continue;
      int lo = 0, hi = u;
      while (lo < hi) {
        int mid = (lo + hi) >> 1;
        float v2 = cv[w2][mid];
        int i2 = ci[w2][mid];
        if (v2 > mv || (v2 == mv && i2 < mi)) lo = mid + 1;
        else hi = mid;
      }
      rank += lo;
    }
    if (rank < u) Mtop[bh * u + rank] = mi;
  }
}

static void run_topk(const float* Mv, int* Mtop, int L, int u,
                     hipStream_t stream) {
  if (L == 2048)      topk_kernel<8><<<32, 256, 0, stream>>>(Mv, Mtop, u);
  else if (L == 1024) topk_kernel<4><<<32, 256, 0, stream>>>(Mv, Mtop, u);
  else                topk_kernel<2><<<32, 256, 0, stream>>>(Mv, Mtop, u);
}

// ---------------- mean of V over L: split-L partial + atomic --------------
__global__ void vmean_zero_kernel(float* __restrict__ vmean) {
  vmean[blockIdx.x * 256 + threadIdx.x] = 0.f;
}

__global__ __launch_bounds__(256) void vmean_partial_kernel(
    const float* __restrict__ V, float* __restrict__ vmean, int L) {
  int b = blockIdx.y;
  int chunk = blockIdx.x;           // 64 chunks
  int rows = L >> 6;
  int t = threadIdx.x;
  const float* base = V + ((size_t)b * L + (size_t)chunk * rows) * D_MODEL;
  float s0 = 0.f, s1 = 0.f;
  for (int r = 0; r < rows; ++r) {
    s0 += base[(size_t)r * D_MODEL + t];
    s1 += base[(size_t)r * D_MODEL + t + 256];
  }
  float invL = 1.0f / (float)L;
  atomicAdd(&vmean[b * D_MODEL + t], s0 * invL);
  atomicAdd(&vmean[b * D_MODEL + t + 256], s1 * invL);
}

__global__ void fill_ctx_kernel(const float* __restrict__ vmean,
                                float* __restrict__ O, int B, int L) {
  int i = blockIdx.x * 256 + threadIdx.x;
  int total = B * L * D_MODEL;
  if (i >= total) return;
  int dcol = i % D_MODEL;
  int b = i / (D_MODEL * L);
  O[i] = vmean[b * D_MODEL + dcol];
}

// ============== attention as batched GEMM pipeline ==============
__global__ void pack_qred_kernel(const float* __restrict__ Q,
                                 const int* __restrict__ Mtop,
                                 float* __restrict__ qred, int L, int U) {
  int z = blockIdx.x;  // bh
  int b = z / NH, h = z % NH;
  int t = threadIdx.x;
  int d = t & 63;
  for (int r = t >> 6; r < 64; r += 4) {
    float v = 0.f;
    if (r < U) {
      int l = Mtop[z * U + r];
      v = Q[((size_t)(b * L + l)) * D_MODEL + h * DH + d];
    }
    qred[((size_t)z * 64 + r) * 64 + d] = v;
  }
}

#define BK 16
#define PADR 4

// S[z][64][L] = 0.125 * Qred[z](64x64) @ K_z^T ; K_z rows stride 512
__global__ __launch_bounds__(256) void scores_gemm_kernel(
    const float* __restrict__ qred, const float* __restrict__ Km,
    float* __restrict__ S, int L) {
  __shared__ float As[BK][64 + PADR];
  __shared__ float Bs[BK][64 + PADR];
  const int z = blockIdx.y;
  const int b = z / NH, h = z % NH;
  const float* A = qred + (size_t)z * 64 * 64;
  const float* Bt = Km + (size_t)b * L * D_MODEL + h * DH;  // ldb = 512
  float* Sz = S + (size_t)z * 64 * L;
  const int bn = blockIdx.x * 64;
  const int tid = threadIdx.x;
  const int tx = tid & 15, ty = tid >> 4;
  const int lr = tid >> 2;
  const int lc = (tid & 3) << 2;
  float acc[4][4] = {};
  for (int k0 = 0; k0 < 64; k0 += BK) {
    float4 av = *(const float4*)(A + (size_t)lr * 64 + k0 + lc);
    float4 bv = *(const float4*)(Bt + (size_t)(bn + lr) * D_MODEL + k0 + lc);
    As[lc + 0][lr] = av.x; As[lc + 1][lr] = av.y;
    As[lc + 2][lr] = av.z; As[lc + 3][lr] = av.w;
    Bs[lc + 0][lr] = bv.x; Bs[lc + 1][lr] = bv.y;
    Bs[lc + 2][lr] = bv.z; Bs[lc + 3][lr] = bv.w;
    __syncthreads();
#pragma unroll
    for (int kk = 0; kk < BK; ++kk) {
      float4 a4 = *(const float4*)&As[kk][ty << 2];
      float4 b4 = *(const float4*)&Bs[kk][tx << 2];
      float ar[4] = {a4.x, a4.y, a4.z, a4.w};
      float br[4] = {b4.x, b4.y, b4.z, b4.w};
#pragma unroll
      for (int i = 0; i < 4; ++i)
#pragma unroll
        for (int j = 0; j < 4; ++j) acc[i][j] += ar[i] * br[j];
    }
    __syncthreads();
  }
#pragma unroll
  for (int i = 0; i < 4; ++i) {
    float* Sr = Sz + (size_t)((ty << 2) + i) * L + bn;
#pragma unroll
    for (int j = 0; j < 4; ++j) Sr[(tx << 2) + j] = 0.125f * acc[i][j];
  }
}

// ---------------- softmax: one block per (z,row) ----------------
template <int LC>
__global__ __launch_bounds__(256) void softmax_kernel(float* __restrict__ S,
                                                      int U) {
  constexpr int NE = LC / 256;
  int rid = blockIdx.x;
  int z = rid / U, r = rid % U;
  float* row = S + (size_t)z * 64 * LC + (size_t)r * LC;
  int t = threadIdx.x;
  float vals[NE];
  float m = -INFINITY;
#pragma unroll
  for (int i = 0; i < NE; ++i) {
    vals[i] = row[t + i * 256];
    m = fmaxf(m, vals[i]);
  }
  __shared__ float red[256];
  red[t] = m;
  __syncthreads();
  for (int s = 128; s > 0; s >>= 1) { if (t < s) red[t] = fmaxf(red[t], red[t + s]); __syncthreads(); }
  m = red[0];
  __syncthreads();
  float sum = 0.f;
#pragma unroll
  for (int i = 0; i < NE; ++i) {
    vals[i] = expf(vals[i] - m);
    sum += vals[i];
  }
  red[t] = sum;
  __syncthreads();
  for (int s = 128; s > 0; s >>= 1) { if (t < s) red[t] += red[t + s]; __syncthreads(); }
  float inv = 1.0f / red[0];
#pragma unroll
  for (int i = 0; i < NE; ++i) row[t + i * 256] = vals[i] * inv;
}

static void run_softmax(float* S, int L, int U, hipStream_t stream) {
  int blocks = 32 * U;
  if (L == 2048)      softmax_kernel<2048><<<blocks, 256, 0, stream>>>(S, U);
  else if (L == 1024) softmax_kernel<1024><<<blocks, 256, 0, stream>>>(S, U);
  else                softmax_kernel<512><<<blocks, 256, 0, stream>>>(S, U);
}

// zero the selected ctx rows before split-K PV atomics
__global__ void zero_sel_kernel(const int* __restrict__ Mtop,
                                float* __restrict__ O, int L, int U) {
  int z = blockIdx.x;
  int b = z / NH, h = z % NH;
  int t = threadIdx.x;
  int d = t & 63;
  for (int r = t >> 6; r < U; r += 4) {
    int l = Mtop[z * U + r];
    O[((size_t)(b * L + l)) * D_MODEL + h * DH + d] = 0.f;
  }
}

// O[sel rows] += P(UxL) @ V(Lx64), split-K over 128-chunks of L.
#define PV_LC 128

template <int U>
__global__ __launch_bounds__(256) void pv_kernel(
    const float* __restrict__ P, const float* __restrict__ V,
    const int* __restrict__ Mtop, float* __restrict__ O, int L) {
  __shared__ float Pl[U][PV_LC];
  __shared__ float Vl[PV_LC][DH + 4];
  const int z = blockIdx.y;
  const int b = z / NH, h = z % NH;
  const int c0 = blockIdx.x * PV_LC;
  const int tid = threadIdx.x;
  const float* Pz = P + (size_t)z * 64 * L + c0;
  for (int i4 = tid; i4 < U * (PV_LC / 4); i4 += 256) {
    int r = i4 / (PV_LC / 4);
    int lq = (i4 % (PV_LC / 4)) * 4;
    float4 p4 = *(const float4*)(Pz + (size_t)r * L + lq);
    Pl[r][lq + 0] = p4.x; Pl[r][lq + 1] = p4.y;
    Pl[r][lq + 2] = p4.z; Pl[r][lq + 3] = p4.w;
  }
  const float* Vb = V + ((size_t)b * L + c0) * D_MODEL + h * DH;
  for (int i4 = tid; i4 < PV_LC * (DH / 4); i4 += 256) {
    int l = i4 >> 4;
    int d4 = (i4 & 15) * 4;
    float4 v4 = *(const float4*)(Vb + (size_t)l * D_MODEL + d4);
    Vl[l][d4 + 0] = v4.x; Vl[l][d4 + 1] = v4.y;
    Vl[l][d4 + 2] = v4.z; Vl[l][d4 + 3] = v4.w;
  }
  __syncthreads();
  const int wave = tid >> 6, lane = tid & 63;
  constexpr int NJ = (U + 3) / 4;
  float acc[NJ] = {};
  for (int l = 0; l < PV_LC; ++l) {
    float vv = Vl[l][lane];
#pragma unroll
    for (int j = 0; j < NJ; ++j) {
      int r = wave + 4 * j;
      if (r < U) acc[j] += Pl[r][l] * vv;
    }
  }
#pragma unroll
  for (int j = 0; j < NJ; ++j) {
    int r = wave + 4 * j;
    if (r < U) {
      int ml = Mtop[z * U + r];
      atomicAdd(&O[((size_t)(b * L + ml)) * D_MODEL + h * DH + lane], acc[j]);
    }
  }
}

static void run_pv(const float* P, const float* V, const int* Mtop, float* O,
                   int L, int U, hipStream_t stream) {
  dim3 gg(L / PV_LC, 32);
  if (U == 40)      pv_kernel<40><<<gg, 256, 0, stream>>>(P, V, Mtop, O, L);
  else if (U == 35) pv_kernel<35><<<gg, 256, 0, stream>>>(P, V, Mtop, O, L);
  else              pv_kernel<64><<<gg, 256, 0, stream>>>(P, V, Mtop, O, L);
}

// ---------------- im2col (circular, K=3) -> bf16 --------------------------
__global__ void im2col_kernel(const float* __restrict__ X,
                              unsigned short* __restrict__ Y, int B, int L) {
  int i = blockIdx.x * 256 + threadIdx.x;
  int total = B * L * 1536;
  if (i >= total) return;
  int ck = i % 1536;
  int l = (i / 1536) % L;
  int b = i / (1536 * L);
  int c = ck / 3, k = ck % 3;
  int lm = l + k - 1;
  if (lm < 0) lm += L;
  else if (lm >= L) lm -= L;
  Y[i] = f2bf(X[((size_t)(b * L + lm)) * D_MODEL + c]);
}

// ---------------- maxpool k=3 s=2, dual fp32/bf16 out ---------------------
__global__ void maxpool_kernel(const float* __restrict__ Y,
                               float* __restrict__ X,
                               unsigned short* __restrict__ Xb, int B, int L) {
  int Lo = L / 2;
  int i = blockIdx.x * 256 + threadIdx.x;
  int total = B * Lo * D_MODEL;
  if (i >= total) return;
  int d = i % D_MODEL;
  int lp = (i / D_MODEL) % Lo;
  int b = i / (D_MODEL * Lo);
  int l0 = 2 * lp - 1;
  float m = -INFINITY;
#pragma unroll
  for (int k = 0; k < 3; ++k) {
    int l = l0 + k;
    if (l >= 0 && l < L) m = fmaxf(m, Y[((size_t)(b * L + l)) * D_MODEL + d]);
  }
  X[i] = m;
  Xb[i] = f2bf(m);
}

// ==========================================================================
extern "C" void kernel_launch(void* const* d_in, const int* in_sizes, int n_in,
                              void* d_out, int out_size, void* d_ws,
                              size_t ws_size, hipStream_t stream) {
  const float* x_enc  = (const float*)d_in[0];
  const float* emb_w  = (const float*)d_in[1];
  const float* Wq     = (const float*)d_in[2];
  const float* bq     = (const float*)d_in[3];
  const float* Wk     = (const float*)d_in[4];
  const float* bk     = (const float*)d_in[5];
  const float* Wv     = (const float*)d_in[6];
  const float* bv     = (const float*)d_in[7];
  const float* Wo     = (const float*)d_in[8];
  const float* bo     = (const float*)d_in[9];
  const float* ln1_g  = (const float*)d_in[10];
  const float* ln1_b  = (const float*)d_in[11];
  const float* ff_w1  = (const float*)d_in[12];
  const float* ff_b1  = (const float*)d_in[13];
  const float* ff_w2  = (const float*)d_in[14];
  const float* ff_b2  = (const float*)d_in[15];
  const float* ln2_g  = (const float*)d_in[16];
  const float* ln2_b  = (const float*)d_in[17];
  const float* cv_w   = (const float*)d_in[18];
  const float* cv_b   = (const float*)d_in[19];
  const float* bn_g   = (const float*)d_in[20];
  const float* bn_b   = (const float*)d_in[21];
  const float* norm_g = (const float*)d_in[22];
  const float* norm_b = (const float*)d_in[23];

  const int B = 4, L0 = 2048, EL = 3;
  const size_t SZ = (size_t)B * 2048 * 512;
  float* ws   = (float*)d_ws;
  float* xbuf = ws;
  float* ebuf = ws + SZ;   // layer0 xb16; pre-LN temp; QKs; Sbuf
  float* qbuf = ws + 2 * SZ;
  float* kbuf = ws + 3 * SZ;
  float* vbuf = ws + 4 * SZ;
  float* obuf = ws + 5 * SZ;
  float* sm   = ws + 6 * SZ;
  int*   d_idx   = (int*)sm;
  float* d_M     = sm + 81920;
  int*   d_Mtop  = (int*)(sm + 81920 + 65536);
  float* d_vmean = sm + 81920 + 65536 + 1280;
  float* qred    = sm;    // reuses idx+M region (dead post-topk)
  float* QKs     = ebuf;
  float* Sbuf    = ebuf;

  const float inv_s = 1.0f / sqrtf(1.0f + 1e-5f);
  auto cast = [&](const float* s, unsigned short* d, int n) {
    cast_bf16_kernel<<<ceil_div(n / 4, 256), 256, 0, stream>>>(s, d, n);
  };

  // layer-0 x bf16 fused into embed (-> ebuf)
  embed_kernel<<<ceil_div(B * L0 * D_MODEL, 256), 256, 0, stream>>>(
      x_enc, emb_w, xbuf, (unsigned short*)ebuf, B, L0);
  unsigned short* xb16 = (unsigned short*)ebuf;  // current layer's bf16 x

  int L = L0;
  for (int i = 0; i < EL; ++i) {
    const int M_ = B * L;
    int c = 5 * (int)ceil(log((double)L));
    int U = c < L ? c : L;
    const float* Wq_i = Wq + (size_t)i * 512 * 512;
    const float* Wk_i = Wk + (size_t)i * 512 * 512;
    const float* Wv_i = Wv + (size_t)i * 512 * 512;
    const float* Wo_i = Wo + (size_t)i * 512 * 512;
    const float* w1_i = ff_w1 + (size_t)i * 512 * 512;
    const float* w2_i = ff_w2 + (size_t)i * 512 * 512;

    // QKV bf16 MFMA. K dual-writes fp32 kbuf (scores) + bf16 k16 (gathers).
    unsigned short* wq16 = (unsigned short*)obuf;
    unsigned short* wk16 = wq16 + 262144;
    unsigned short* wv16 = wq16 + 524288;
    unsigned short* k16  = wq16 + 1048576;  // obuf bytes [2MB, 2MB+M_*1KB)
    {
      cast(Wq_i, wq16, 512 * 512);
      cast(Wk_i, wk16, 512 * 512);
      cast(Wv_i, wv16, 512 * 512);
      run_bgemm<0, 1>(xb16, wq16, bq + i * 512, nullptr, nullptr, nullptr,
                      qbuf, nullptr, M_, 512, 512, 0.f, stream);
      run_bgemm<0, 3>(xb16, wk16, bk + i * 512, nullptr, nullptr, nullptr,
                      kbuf, k16, M_, 512, 512, 0.f, stream);
      run_bgemm<0, 1>(xb16, wv16, bv + i * 512, nullptr, nullptr, nullptr,
                      vbuf, nullptr, M_, 512, 512, 0.f, stream);
    }

    uint32_t lk0, lk1, k20, k21;
    threefry2x32(0u, 42u, 0u, (uint32_t)i, &lk0, &lk1);
    threefry2x32(lk0, lk1, 0u, 1u, &k20, &k21);
    idx_kernel<<<ceil_div(L * U, 256), 256, 0, stream>>>(d_idx, L, U, k20, k21);

    sparse_qk_kernel<<<B * L, 256, 0, stream>>>(qbuf, k16, d_idx, QKs, B, L, U);
    sparse_reduce_kernel<<<ceil_div(B * NH * L * 64, 256), 256, 0, stream>>>(
        QKs, d_M, B * NH * L, L, U);
    run_topk(d_M, d_Mtop, L, U, stream);
    vmean_zero_kernel<<<8, 256, 0, stream>>>(d_vmean);
    vmean_partial_kernel<<<dim3(64, B), 256, 0, stream>>>(vbuf, d_vmean, L);
    fill_ctx_kernel<<<ceil_div(B * L * D_MODEL, 256), 256, 0, stream>>>(
        d_vmean, obuf, B, L);

    pack_qred_kernel<<<B * NH, 256, 0, stream>>>(qbuf, d_Mtop, qred, L, U);
    scores_gemm_kernel<<<dim3(L / 64, B * NH), 256, 0, stream>>>(qred, kbuf,
                                                                 Sbuf, L);
    run_softmax(Sbuf, L, U, stream);
    zero_sel_kernel<<<B * NH, 256, 0, stream>>>(d_Mtop, obuf, L, U);
    run_pv(Sbuf, vbuf, d_Mtop, obuf, L, U, stream);

    // O-proj: ctx cast -> qbuf shorts (Q dead), Wo -> kbuf shorts (K dead)
    unsigned short* ab16 = (unsigned short*)qbuf;
    unsigned short* wb16 = (unsigned short*)kbuf;
    cast(obuf, ab16, M_ * 512);
    cast(Wo_i, wb16, 512 * 512);
    run_bgemm<2, 1>(ab16, wb16, bo + i * 512, xbuf, nullptr, nullptr, ebuf,
                    nullptr, M_, 512, 512, 0.f, stream);
    // ln1 dual-writes x fp32 + bf16 (FF1 A input) -> qbuf shorts
    ln_dual_kernel<<<M_, 256, 0, stream>>>(ebuf, ln1_g + i * 512,
                                           ln1_b + i * 512, xbuf, ab16);

    // FF1: bf16-only output (consumed solely as FF2's A) -> obuf shorts
    unsigned short* ff1b16 = (unsigned short*)obuf;
    cast(w1_i, wb16, 512 * 512);
    run_bgemm<1, 2>(ab16, wb16, ff_b1 + i * 512, nullptr, nullptr, nullptr,
                    nullptr, ff1b16, M_, 512, 512, 0.f, stream);
    // FF2 (+residual) -> ebuf fp32
    cast(w2_i, wb16, 512 * 512);
    run_bgemm<2, 1>(ff1b16, wb16, ff_b2 + i * 512, xbuf, nullptr, nullptr,
                    ebuf, nullptr, M_, 512, 512, 0.f, stream);
    ln_kernel<<<M_, 256, 0, stream>>>(ebuf, ln2_g + i * 512, ln2_b + i * 512, xbuf);

    if (i < EL - 1) {
      // conv distill: im2col -> qbuf(+kbuf) shorts, weights -> vbuf shorts
      unsigned short* imb16 = (unsigned short*)qbuf;
      unsigned short* wb16c = (unsigned short*)vbuf;
      im2col_kernel<<<ceil_div(B * L * 1536, 256), 256, 0, stream>>>(xbuf, imb16, B, L);
      cast(cv_w + (size_t)i * 512 * 1536, wb16c, 512 * 1536);
      run_bgemm<3, 1>(imb16, wb16c, cv_b + i * 512, nullptr, bn_g + i * 512,
                      bn_b + i * 512, ebuf, nullptr, M_, 512, 1536, inv_s,
                      stream);
      // maxpool dual-writes next-layer x fp32 + bf16 @ vbuf tail (V dead;
      // next layer's V-proj writes only vbuf[0, M_/2*512*4B) -- no overlap)
      xb16 = (unsigned short*)vbuf + 6291456;  // byte offset 12.6MB
      maxpool_kernel<<<ceil_div(B * (L / 2) * D_MODEL, 256), 256, 0, stream>>>(
          ebuf, xbuf, xb16, B, L);
      L /= 2;
    }
  }

  ln_kernel<<<B * L, 256, 0, stream>>>(xbuf, norm_g, norm_b, (float*)d_out);
}